// Round 15
// baseline (2656.670 us; speedup 1.0000x reference)
//
#include <hip/hip_runtime.h>

// FBSNN: 50-step SDE loop, two 2-64-64-1 MLPs (Q control, Y value + dY/dy tangent).
// R15 (from R14 @482us, VGPR=128 with a TWO-tile body): VALU 68% + MFMA 31% = 99%
// with no pipe overlap => TLP-starved at 2 waves/SIMD. Revert to 1-tile waves
// (grid 1024) with __launch_bounds__(256,4): the 1-tile body is strictly smaller
// than the 2-tile body that PROVABLY fits 128 regs, so the cap is safe (unlike
// R8/R10 where demand > cap). 4 waves/SIMD = 4096 slots = 4096 waves, single
// phase, 2x TLP for MFMA/VALU pipe overlap.

#define B_TOT 262144
#define NSTEPS 50
#define DT 0.01f
#define SIGMA 0.5f

typedef _Float16 half8_t  __attribute__((ext_vector_type(8)));
typedef __fp16   fp16x2   __attribute__((ext_vector_type(2)));
typedef float    float4_t __attribute__((ext_vector_type(4)));
typedef int      int4_t   __attribute__((ext_vector_type(4)));

#define MFMA(a, b, c) __builtin_amdgcn_mfma_f32_16x16x32_f16((a), (b), (c), 0, 0, 0)

__device__ __forceinline__ half8_t pack4(fp16x2 a, fp16x2 b, fp16x2 c, fp16x2 d) {
    int4_t t;
    t[0] = __builtin_bit_cast(int, a);
    t[1] = __builtin_bit_cast(int, b);
    t[2] = __builtin_bit_cast(int, c);
    t[3] = __builtin_bit_cast(int, d);
    return __builtin_bit_cast(half8_t, t);
}
__device__ __forceinline__ fp16x2 as_h2(int v) { return __builtin_bit_cast(fp16x2, v); }

// horizontal add of the two fp16 halves (result in both halves)
__device__ __forceinline__ fp16x2 hswap_add(fp16x2 v) {
    unsigned u = __builtin_bit_cast(unsigned, v);
    unsigned s = (u >> 16) | (u << 16);
    return v + __builtin_bit_cast(fp16x2, s);
}
// reduce across the 4 g-groups: xor16 (ds_swizzle) + xor32 (shfl)
__device__ __forceinline__ fp16x2 cross_g_add(fp16x2 v) {
    int o = __builtin_amdgcn_ds_swizzle(__builtin_bit_cast(int, v), 0x401F); // xor 16
    v = v + __builtin_bit_cast(fp16x2, o);
    int p = __shfl_xor(__builtin_bit_cast(int, v), 32, 64);
    v = v + __builtin_bit_cast(fp16x2, p);
    return v;
}

__device__ __forceinline__ float uniform_f(float x) {
    return __builtin_bit_cast(float, __builtin_amdgcn_readfirstlane(__builtin_bit_cast(int, x)));
}

__global__ void zero_out_k(float* out) { out[0] = 0.f; }

__global__ __launch_bounds__(256, 4) void fbsnn_k(
    const float* __restrict__ dW,  const float* __restrict__ y0i,
    const float* __restrict__ Yw1, const float* __restrict__ Yb1,
    const float* __restrict__ Yw2, const float* __restrict__ Yb2,
    const float* __restrict__ Yw3, const float* __restrict__ Yb3,
    const float* __restrict__ Qw1, const float* __restrict__ Qb1,
    const float* __restrict__ Qw2, const float* __restrict__ Qb2,
    const float* __restrict__ Qw3, const float* __restrict__ Qb3,
    float* __restrict__ out)
{
    // W2 transposed staging: w2[n*72 + k] = W2[k*64 + n]; read ONCE into registers.
    __shared__ __align__(16) _Float16 w2q[64 * 72];
    __shared__ __align__(16) _Float16 w2y[64 * 72];
    // layer1 consts fp32: [0..63]=w1_t row, [64..127]=w1_y row, [128..191]=b1
    __shared__ __align__(16) float l1q[192];
    __shared__ __align__(16) float l1y[192];
    // epilogue consts packed fp16x2-as-int: cons[net][g][nt] = {b2_01,b2_23,w3_01,w3_23}
    __shared__ __align__(16) int cons[2][4][4][4];
    __shared__ float rb[4];

    const int tid = threadIdx.x;

    #pragma unroll
    for (int it = 0; it < 16; ++it) {
        int e = it * 256 + tid;
        int k = e >> 6, n = e & 63;
        w2q[n * 72 + k] = (_Float16)Qw2[e];
        w2y[n * 72 + k] = (_Float16)Yw2[e];
    }
    if (tid < 64) {
        l1q[tid] = Qw1[tid]; l1q[64 + tid] = Qw1[64 + tid]; l1q[128 + tid] = Qb1[tid];
        l1y[tid] = Yw1[tid]; l1y[64 + tid] = Yw1[64 + tid]; l1y[128 + tid] = Yb1[tid];
    }
    if (tid < 128) {
        int net = tid >> 6, gg = (tid >> 4) & 3, nt = (tid >> 2) & 3, sl = tid & 3;
        const float* src = (sl < 2) ? (net ? Yb2 : Qb2) : (net ? Yw3 : Qw3);
        int nb = nt * 16 + gg * 4 + (sl & 1) * 2;
        fp16x2 v = __builtin_amdgcn_cvt_pkrtz(src[nb], src[nb + 1]);
        cons[net][gg][nt][sl] = __builtin_bit_cast(int, v);
    }
    __syncthreads();

    const int lane = tid & 63;
    const int wv   = tid >> 6;
    const int g    = lane >> 4;     // quad group 0..3
    const int c    = lane & 15;     // column within tile (= sample col)
    const int sG   = blockIdx.x * 256 + wv * 64 + lane;   // global sample
    const int k0   = g * 8;         // this lane's k-slice base

    // ---- ALL weight fragments held in registers for the whole loop (32 VGPRs) ----
    half8_t wfq[4][2], wfy[4][2];
    #pragma unroll
    for (int nt = 0; nt < 4; ++nt) {
        const _Float16* bq = &w2q[(c + 16 * nt) * 72 + k0];
        const _Float16* by = &w2y[(c + 16 * nt) * 72 + k0];
        wfq[nt][0] = *(const half8_t*)bq;
        wfq[nt][1] = *(const half8_t*)(bq + 32);
        wfy[nt][0] = *(const half8_t*)by;
        wfy[nt][1] = *(const half8_t*)(by + 32);
    }

    // packed layer-1 y-row weights, held in regs for the whole loop
    fp16x2 wqh[8], wyh[8];
    #pragma unroll
    for (int j = 0; j < 8; ++j) {
        int idx = (j < 4) ? (k0 + 2 * j) : (32 + k0 + 2 * (j - 4));
        wqh[j] = fp16x2{(__fp16)l1q[64 + idx], (__fp16)l1q[64 + idx + 1]};
        wyh[j] = fp16x2{(__fp16)l1y[64 + idx], (__fp16)l1y[64 + idx + 1]};
    }

    const float qb3 = uniform_f(Qb3[0]);
    const float yb3 = uniform_f(Yb3[0]);

    const fp16x2 zero2 = {(__fp16)0.f, (__fp16)0.f};
    const fp16x2 one2  = {(__fp16)1.f, (__fp16)1.f};
    const fp16x2 big2  = {(__fp16)32768.f, (__fp16)32768.f};

    float y = y0i[0];
    float t = 0.f;
    float resid_base = 0.f, loss = 0.f;
    float Y = 0.f;
    float dw_next = dW[sG];

    // NSTEPS+1 fused evals, ONE call site.
    #pragma unroll 1
    for (int it = 0; it <= NSTEPS; ++it) {
        float dw = dw_next;
        int sn = (it < NSTEPS - 1) ? (it + 1) : (NSTEPS - 1);
        dw_next = dW[(size_t)sn * B_TOT + sG];

        // ======== fused eval of BOTH nets at (t, y) -> q, Y, dY ========
        float q, dY;
        {
            // a-vector (t-dependent part of layer 1), packed fp16
            fp16x2 aqh[8], ayh[8];
            #pragma unroll
            for (int h = 0; h < 2; ++h) {
                int kk = k0 + 32 * h;
                float4_t qt0 = *(const float4_t*)&l1q[kk];
                float4_t qt1 = *(const float4_t*)&l1q[kk + 4];
                float4_t qc0 = *(const float4_t*)&l1q[128 + kk];
                float4_t qc1 = *(const float4_t*)&l1q[128 + kk + 4];
                float4_t yt0 = *(const float4_t*)&l1y[kk];
                float4_t yt1 = *(const float4_t*)&l1y[kk + 4];
                float4_t yc0 = *(const float4_t*)&l1y[128 + kk];
                float4_t yc1 = *(const float4_t*)&l1y[128 + kk + 4];
                #pragma unroll
                for (int j = 0; j < 2; ++j) {
                    float a0 = fmaf(t, qt0[2 * j], qc0[2 * j]);
                    float a1 = fmaf(t, qt0[2 * j + 1], qc0[2 * j + 1]);
                    float a2 = fmaf(t, qt1[2 * j], qc1[2 * j]);
                    float a3 = fmaf(t, qt1[2 * j + 1], qc1[2 * j + 1]);
                    aqh[4 * h + j]     = __builtin_amdgcn_cvt_pkrtz(a0, a1);
                    aqh[4 * h + 2 + j] = __builtin_amdgcn_cvt_pkrtz(a2, a3);
                    float b0 = fmaf(t, yt0[2 * j], yc0[2 * j]);
                    float b1 = fmaf(t, yt0[2 * j + 1], yc0[2 * j + 1]);
                    float b2 = fmaf(t, yt1[2 * j], yc1[2 * j]);
                    float b3 = fmaf(t, yt1[2 * j + 1], yc1[2 * j + 1]);
                    ayh[4 * h + j]     = __builtin_amdgcn_cvt_pkrtz(b0, b1);
                    ayh[4 * h + 2 + j] = __builtin_amdgcn_cvt_pkrtz(b2, b3);
                }
            }

            fp16x2 qsel = zero2, fsel = zero2, dsel = zero2;
            #pragma unroll
            for (int mt = 0; mt < 4; ++mt) {
                float ym = __shfl(y, mt * 16 + c, 64);
                fp16x2 ym2 = __builtin_amdgcn_cvt_pkrtz(ym, ym);

                fp16x2 hqa[8], hya[8], tda[8];
                #pragma unroll
                for (int j = 0; j < 8; ++j) {
                    hqa[j] = __builtin_elementwise_max((fp16x2)(wqh[j] * ym2 + aqh[j]), zero2);
                    fp16x2 hy = __builtin_elementwise_max((fp16x2)(wyh[j] * ym2 + ayh[j]), zero2);
                    hya[j] = hy;
                    fp16x2 mk = __builtin_elementwise_min((fp16x2)(hy * big2), one2);
                    tda[j] = mk * wyh[j];
                }
                half8_t qa_lo = pack4(hqa[0], hqa[1], hqa[2], hqa[3]);
                half8_t qa_hi = pack4(hqa[4], hqa[5], hqa[6], hqa[7]);
                half8_t yf_lo = pack4(hya[0], hya[1], hya[2], hya[3]);
                half8_t yf_hi = pack4(hya[4], hya[5], hya[6], hya[7]);
                half8_t td_lo = pack4(tda[0], tda[1], tda[2], tda[3]);
                half8_t td_hi = pack4(tda[4], tda[5], tda[6], tda[7]);

                fp16x2 pq01 = zero2, pq23 = zero2;
                fp16x2 pf01 = zero2, pf23 = zero2;
                fp16x2 pd01 = zero2, pd23 = zero2;
                #pragma unroll
                for (int nt = 0; nt < 4; ++nt) {
                    float4_t cq = {}, cf = {}, ct = {};
                    cq = MFMA(wfq[nt][0], qa_lo, cq);
                    cq = MFMA(wfq[nt][1], qa_hi, cq);
                    cf = MFMA(wfy[nt][0], yf_lo, cf);
                    cf = MFMA(wfy[nt][1], yf_hi, cf);
                    ct = MFMA(wfy[nt][0], td_lo, ct);
                    ct = MFMA(wfy[nt][1], td_hi, ct);
                    const int4_t kq = *(const int4_t*)cons[0][g][nt];
                    const int4_t ky = *(const int4_t*)cons[1][g][nt];
                    fp16x2 cq01 = __builtin_amdgcn_cvt_pkrtz(cq[0], cq[1]);
                    fp16x2 cq23 = __builtin_amdgcn_cvt_pkrtz(cq[2], cq[3]);
                    fp16x2 vq01 = __builtin_elementwise_max((fp16x2)(cq01 + as_h2(kq[0])), zero2);
                    fp16x2 vq23 = __builtin_elementwise_max((fp16x2)(cq23 + as_h2(kq[1])), zero2);
                    pq01 = vq01 * as_h2(kq[2]) + pq01;
                    pq23 = vq23 * as_h2(kq[3]) + pq23;
                    fp16x2 cf01 = __builtin_amdgcn_cvt_pkrtz(cf[0], cf[1]);
                    fp16x2 cf23 = __builtin_amdgcn_cvt_pkrtz(cf[2], cf[3]);
                    fp16x2 hf01 = __builtin_elementwise_max((fp16x2)(cf01 + as_h2(ky[0])), zero2);
                    fp16x2 hf23 = __builtin_elementwise_max((fp16x2)(cf23 + as_h2(ky[1])), zero2);
                    pf01 = hf01 * as_h2(ky[2]) + pf01;
                    pf23 = hf23 * as_h2(ky[3]) + pf23;
                    fp16x2 mm01 = __builtin_elementwise_min((fp16x2)(hf01 * big2), one2);
                    fp16x2 mm23 = __builtin_elementwise_min((fp16x2)(hf23 * big2), one2);
                    fp16x2 ct01 = __builtin_amdgcn_cvt_pkrtz(ct[0], ct[1]);
                    fp16x2 ct23 = __builtin_amdgcn_cvt_pkrtz(ct[2], ct[3]);
                    pd01 = (ct01 * mm01) * as_h2(ky[2]) + pd01;
                    pd23 = (ct23 * mm23) * as_h2(ky[3]) + pd23;
                }
                fp16x2 sq = cross_g_add(hswap_add(pq01 + pq23));
                fp16x2 sf = cross_g_add(hswap_add(pf01 + pf23));
                fp16x2 sd = cross_g_add(hswap_add(pd01 + pd23));
                if (mt == g) { qsel = sq; fsel = sf; dsel = sd; }
            }
            q  = (float)qsel[0] + qb3;
            Y  = (float)fsel[0] + yb3;
            dY = (float)dsel[0];
        }
        // ======== end fused eval ========

        if (it > 0) {
            float resid = Y - resid_base;
            loss = fmaf(resid, resid, loss);
        }
        if (it < NSTEPS) {
            resid_base = fmaf(SIGMA * dY, dw, fmaf(-0.5f * DT, q * q, Y));
            y = fmaf(SIGMA, dw, fmaf(q, DT, y));
            t += DT;
        }
    }

    // terminal: (YN - yN^2)^2
    float tm = Y - y * y;
    loss = fmaf(tm, tm, loss);

    #pragma unroll
    for (int off = 1; off < 64; off <<= 1) loss += __shfl_xor(loss, off, 64);
    if (lane == 0) rb[wv] = loss;
    __syncthreads();
    if (tid == 0) atomicAdd(out, (rb[0] + rb[1] + rb[2] + rb[3]) * (1.0f / (float)B_TOT));
}

extern "C" void kernel_launch(void* const* d_in, const int* in_sizes, int n_in,
                              void* d_out, int out_size, void* d_ws, size_t ws_size,
                              hipStream_t stream) {
    const float* dW  = (const float*)d_in[0];
    const float* y0i = (const float*)d_in[1];
    const float* Yw1 = (const float*)d_in[2];
    const float* Yb1 = (const float*)d_in[3];
    const float* Yw2 = (const float*)d_in[4];
    const float* Yb2 = (const float*)d_in[5];
    const float* Yw3 = (const float*)d_in[6];
    const float* Yb3 = (const float*)d_in[7];
    const float* Qw1 = (const float*)d_in[8];
    const float* Qb1 = (const float*)d_in[9];
    const float* Qw2 = (const float*)d_in[10];
    const float* Qb2 = (const float*)d_in[11];
    const float* Qw3 = (const float*)d_in[12];
    const float* Qb3 = (const float*)d_in[13];
    float* out = (float*)d_out;

    hipLaunchKernelGGL(zero_out_k, dim3(1), dim3(1), 0, stream, out);
    hipLaunchKernelGGL(fbsnn_k, dim3(B_TOT / 256), dim3(256), 0, stream,
                       dW, y0i, Yw1, Yb1, Yw2, Yb2, Yw3, Yb3,
                       Qw1, Qb1, Qw2, Qb2, Qw3, Qb3, out);
}

// Round 16
// 513.448 us; speedup vs baseline: 5.1742x; 5.1742x over previous
//
#include <hip/hip_runtime.h>

// FBSNN: 50-step SDE loop, two 2-64-64-1 MLPs (Q control, Y value + dY/dy tangent).
// R16 (from R14 @482us, 2-tile waves, single phase, VGPR 128 of 256 budget):
// spend the register headroom on issue efficiency:
//  (1) epilogue consts LDS->registers (kills 64 ds_read_b128/step + lgkm waits);
//  (2) layer-2 bias folded into fp32 MFMA C-init (deletes 128 pk-adds/step);
//  (3) two tiles share ONE cross-lane reduction (tile0 in low half, tile1 in high).
// NEVER set min-waves >= 3 (R8/R10/R15: allocator collapses to VGPR 64 + scratch).

#define B_TOT 262144
#define NSTEPS 50
#define DT 0.01f
#define SIGMA 0.5f

typedef _Float16 half8_t  __attribute__((ext_vector_type(8)));
typedef __fp16   fp16x2   __attribute__((ext_vector_type(2)));
typedef float    float4_t __attribute__((ext_vector_type(4)));
typedef int      int4_t   __attribute__((ext_vector_type(4)));

#define MFMA(a, b, c) __builtin_amdgcn_mfma_f32_16x16x32_f16((a), (b), (c), 0, 0, 0)

__device__ __forceinline__ half8_t pack4(fp16x2 a, fp16x2 b, fp16x2 c, fp16x2 d) {
    int4_t t;
    t[0] = __builtin_bit_cast(int, a);
    t[1] = __builtin_bit_cast(int, b);
    t[2] = __builtin_bit_cast(int, c);
    t[3] = __builtin_bit_cast(int, d);
    return __builtin_bit_cast(half8_t, t);
}

// horizontal add of the two fp16 halves (result in both halves)
__device__ __forceinline__ fp16x2 hswap_add(fp16x2 v) {
    unsigned u = __builtin_bit_cast(unsigned, v);
    unsigned s = (u >> 16) | (u << 16);
    return v + __builtin_bit_cast(fp16x2, s);
}
// merge: low half from a, high half from b
__device__ __forceinline__ fp16x2 merge_lo_hi(fp16x2 a, fp16x2 b) {
    unsigned ua = __builtin_bit_cast(unsigned, a);
    unsigned ub = __builtin_bit_cast(unsigned, b);
    return __builtin_bit_cast(fp16x2, (ua & 0xffffu) | (ub & 0xffff0000u));
}
// reduce across the 4 g-groups: xor16 (ds_swizzle) + xor32 (shfl)
__device__ __forceinline__ fp16x2 cross_g_add(fp16x2 v) {
    int o = __builtin_amdgcn_ds_swizzle(__builtin_bit_cast(int, v), 0x401F); // xor 16
    v = v + __builtin_bit_cast(fp16x2, o);
    int p = __shfl_xor(__builtin_bit_cast(int, v), 32, 64);
    v = v + __builtin_bit_cast(fp16x2, p);
    return v;
}

__device__ __forceinline__ float uniform_f(float x) {
    return __builtin_bit_cast(float, __builtin_amdgcn_readfirstlane(__builtin_bit_cast(int, x)));
}

__global__ void zero_out_k(float* out) { out[0] = 0.f; }

__global__ __launch_bounds__(256, 2) void fbsnn_k(
    const float* __restrict__ dW,  const float* __restrict__ y0i,
    const float* __restrict__ Yw1, const float* __restrict__ Yb1,
    const float* __restrict__ Yw2, const float* __restrict__ Yb2,
    const float* __restrict__ Yw3, const float* __restrict__ Yb3,
    const float* __restrict__ Qw1, const float* __restrict__ Qb1,
    const float* __restrict__ Qw2, const float* __restrict__ Qb2,
    const float* __restrict__ Qw3, const float* __restrict__ Qb3,
    float* __restrict__ out)
{
    // W2 transposed staging: w2[n*72 + k] = W2[k*64 + n]; read ONCE into registers.
    __shared__ __align__(16) _Float16 w2q[64 * 72];
    __shared__ __align__(16) _Float16 w2y[64 * 72];
    // layer1 consts fp32: [0..63]=w1_t row, [64..127]=w1_y row, [128..191]=b1
    __shared__ __align__(16) float l1q[192];
    __shared__ __align__(16) float l1y[192];
    __shared__ float rb[4];

    const int tid = threadIdx.x;

    #pragma unroll
    for (int it = 0; it < 16; ++it) {
        int e = it * 256 + tid;
        int k = e >> 6, n = e & 63;
        w2q[n * 72 + k] = (_Float16)Qw2[e];
        w2y[n * 72 + k] = (_Float16)Yw2[e];
    }
    if (tid < 64) {
        l1q[tid] = Qw1[tid]; l1q[64 + tid] = Qw1[64 + tid]; l1q[128 + tid] = Qb1[tid];
        l1y[tid] = Yw1[tid]; l1y[64 + tid] = Yw1[64 + tid]; l1y[128 + tid] = Yb1[tid];
    }
    __syncthreads();

    const int lane = tid & 63;
    const int wv   = tid >> 6;
    const int g    = lane >> 4;     // quad group 0..3
    const int c    = lane & 15;     // column within tile (= sample col)
    const int sA   = blockIdx.x * 512 + wv * 128 + lane;  // tile-0 global sample
    const int k0   = g * 8;         // this lane's k-slice base

    // ---- ALL weight fragments held in registers for the whole loop (32 VGPRs) ----
    half8_t wfq[4][2], wfy[4][2];
    #pragma unroll
    for (int nt = 0; nt < 4; ++nt) {
        const _Float16* bq = &w2q[(c + 16 * nt) * 72 + k0];
        const _Float16* by = &w2y[(c + 16 * nt) * 72 + k0];
        wfq[nt][0] = *(const half8_t*)bq;
        wfq[nt][1] = *(const half8_t*)(bq + 32);
        wfy[nt][0] = *(const half8_t*)by;
        wfy[nt][1] = *(const half8_t*)(by + 32);
    }

    // packed layer-1 y-row weights, held in regs for the whole loop
    fp16x2 wqh[8], wyh[8];
    #pragma unroll
    for (int j = 0; j < 8; ++j) {
        int idx = (j < 4) ? (k0 + 2 * j) : (32 + k0 + 2 * (j - 4));
        wqh[j] = fp16x2{(__fp16)l1q[64 + idx], (__fp16)l1q[64 + idx + 1]};
        wyh[j] = fp16x2{(__fp16)l1y[64 + idx], (__fp16)l1y[64 + idx + 1]};
    }

    // epilogue consts in registers: fp32 biases for C-init (per nt,r) + packed w3
    float bq2f[16], by2f[16];
    fp16x2 qw3h[8], yw3h[8];
    #pragma unroll
    for (int nt = 0; nt < 4; ++nt) {
        #pragma unroll
        for (int r = 0; r < 4; ++r) {
            int nb = nt * 16 + g * 4 + r;
            bq2f[4 * nt + r] = Qb2[nb];
            by2f[4 * nt + r] = Yb2[nb];
        }
        #pragma unroll
        for (int p = 0; p < 2; ++p) {
            int nb = nt * 16 + g * 4 + 2 * p;
            qw3h[2 * nt + p] = __builtin_amdgcn_cvt_pkrtz(Qw3[nb], Qw3[nb + 1]);
            yw3h[2 * nt + p] = __builtin_amdgcn_cvt_pkrtz(Yw3[nb], Yw3[nb + 1]);
        }
    }

    const float qb3 = uniform_f(Qb3[0]);
    const float yb3 = uniform_f(Yb3[0]);

    const fp16x2 zero2 = {(__fp16)0.f, (__fp16)0.f};
    const fp16x2 one2  = {(__fp16)1.f, (__fp16)1.f};
    const fp16x2 big2  = {(__fp16)32768.f, (__fp16)32768.f};

    // two independent sample tiles per wave
    float yS[2], residS[2], YS[2], dwn[2];
    yS[0] = y0i[0];      yS[1] = yS[0];
    residS[0] = 0.f;     residS[1] = 0.f;
    YS[0] = 0.f;         YS[1] = 0.f;
    dwn[0] = dW[sA];     dwn[1] = dW[sA + 64];
    float t = 0.f, loss = 0.f;

    // NSTEPS+1 fused evals, ONE call site.
    #pragma unroll 1
    for (int it = 0; it <= NSTEPS; ++it) {
        float dwc[2] = {dwn[0], dwn[1]};
        int sn = (it < NSTEPS - 1) ? (it + 1) : (NSTEPS - 1);
        dwn[0] = dW[(size_t)sn * B_TOT + sA];
        dwn[1] = dW[(size_t)sn * B_TOT + sA + 64];

        // a-vector (t-dependent part of layer 1), packed fp16 — SHARED by both tiles
        fp16x2 aqh[8], ayh[8];
        #pragma unroll
        for (int h = 0; h < 2; ++h) {
            int kk = k0 + 32 * h;
            float4_t qt0 = *(const float4_t*)&l1q[kk];
            float4_t qt1 = *(const float4_t*)&l1q[kk + 4];
            float4_t qc0 = *(const float4_t*)&l1q[128 + kk];
            float4_t qc1 = *(const float4_t*)&l1q[128 + kk + 4];
            float4_t yt0 = *(const float4_t*)&l1y[kk];
            float4_t yt1 = *(const float4_t*)&l1y[kk + 4];
            float4_t yc0 = *(const float4_t*)&l1y[128 + kk];
            float4_t yc1 = *(const float4_t*)&l1y[128 + kk + 4];
            #pragma unroll
            for (int j = 0; j < 2; ++j) {
                float a0 = fmaf(t, qt0[2 * j], qc0[2 * j]);
                float a1 = fmaf(t, qt0[2 * j + 1], qc0[2 * j + 1]);
                float a2 = fmaf(t, qt1[2 * j], qc1[2 * j]);
                float a3 = fmaf(t, qt1[2 * j + 1], qc1[2 * j + 1]);
                aqh[4 * h + j]     = __builtin_amdgcn_cvt_pkrtz(a0, a1);
                aqh[4 * h + 2 + j] = __builtin_amdgcn_cvt_pkrtz(a2, a3);
                float b0 = fmaf(t, yt0[2 * j], yc0[2 * j]);
                float b1 = fmaf(t, yt0[2 * j + 1], yc0[2 * j + 1]);
                float b2 = fmaf(t, yt1[2 * j], yc1[2 * j]);
                float b3 = fmaf(t, yt1[2 * j + 1], yc1[2 * j + 1]);
                ayh[4 * h + j]     = __builtin_amdgcn_cvt_pkrtz(b0, b1);
                ayh[4 * h + 2 + j] = __builtin_amdgcn_cvt_pkrtz(b2, b3);
            }
        }

        fp16x2 qsel = zero2, fsel = zero2, dsel = zero2;  // low=tile0, high=tile1
        #pragma unroll
        for (int mt = 0; mt < 4; ++mt) {
            fp16x2 hsq[2], hsf[2], hsd[2];
            #pragma unroll
            for (int tl = 0; tl < 2; ++tl) {
                float ym = __shfl(yS[tl], mt * 16 + c, 64);
                fp16x2 ym2 = __builtin_amdgcn_cvt_pkrtz(ym, ym);

                fp16x2 hqa[8], hya[8], tda[8];
                #pragma unroll
                for (int j = 0; j < 8; ++j) {
                    hqa[j] = __builtin_elementwise_max((fp16x2)(wqh[j] * ym2 + aqh[j]), zero2);
                    fp16x2 hy = __builtin_elementwise_max((fp16x2)(wyh[j] * ym2 + ayh[j]), zero2);
                    hya[j] = hy;
                    fp16x2 mk = __builtin_elementwise_min((fp16x2)(hy * big2), one2);
                    tda[j] = mk * wyh[j];
                }
                half8_t qa_lo = pack4(hqa[0], hqa[1], hqa[2], hqa[3]);
                half8_t qa_hi = pack4(hqa[4], hqa[5], hqa[6], hqa[7]);
                half8_t yf_lo = pack4(hya[0], hya[1], hya[2], hya[3]);
                half8_t yf_hi = pack4(hya[4], hya[5], hya[6], hya[7]);
                half8_t td_lo = pack4(tda[0], tda[1], tda[2], tda[3]);
                half8_t td_hi = pack4(tda[4], tda[5], tda[6], tda[7]);

                fp16x2 pq01 = zero2, pq23 = zero2;
                fp16x2 pf01 = zero2, pf23 = zero2;
                fp16x2 pd01 = zero2, pd23 = zero2;
                #pragma unroll
                for (int nt = 0; nt < 4; ++nt) {
                    // bias pre-loaded into fp32 accumulators (saves fp16 bias adds)
                    float4_t cq = {bq2f[4 * nt], bq2f[4 * nt + 1], bq2f[4 * nt + 2], bq2f[4 * nt + 3]};
                    float4_t cf = {by2f[4 * nt], by2f[4 * nt + 1], by2f[4 * nt + 2], by2f[4 * nt + 3]};
                    float4_t ct = {};
                    cq = MFMA(wfq[nt][0], qa_lo, cq);
                    cq = MFMA(wfq[nt][1], qa_hi, cq);
                    cf = MFMA(wfy[nt][0], yf_lo, cf);
                    cf = MFMA(wfy[nt][1], yf_hi, cf);
                    ct = MFMA(wfy[nt][0], td_lo, ct);
                    ct = MFMA(wfy[nt][1], td_hi, ct);
                    fp16x2 cq01 = __builtin_amdgcn_cvt_pkrtz(cq[0], cq[1]);
                    fp16x2 cq23 = __builtin_amdgcn_cvt_pkrtz(cq[2], cq[3]);
                    fp16x2 vq01 = __builtin_elementwise_max(cq01, zero2);
                    fp16x2 vq23 = __builtin_elementwise_max(cq23, zero2);
                    pq01 = vq01 * qw3h[2 * nt] + pq01;
                    pq23 = vq23 * qw3h[2 * nt + 1] + pq23;
                    fp16x2 cf01 = __builtin_amdgcn_cvt_pkrtz(cf[0], cf[1]);
                    fp16x2 cf23 = __builtin_amdgcn_cvt_pkrtz(cf[2], cf[3]);
                    fp16x2 hf01 = __builtin_elementwise_max(cf01, zero2);
                    fp16x2 hf23 = __builtin_elementwise_max(cf23, zero2);
                    pf01 = hf01 * yw3h[2 * nt] + pf01;
                    pf23 = hf23 * yw3h[2 * nt + 1] + pf23;
                    fp16x2 mm01 = __builtin_elementwise_min((fp16x2)(hf01 * big2), one2);
                    fp16x2 mm23 = __builtin_elementwise_min((fp16x2)(hf23 * big2), one2);
                    fp16x2 ct01 = __builtin_amdgcn_cvt_pkrtz(ct[0], ct[1]);
                    fp16x2 ct23 = __builtin_amdgcn_cvt_pkrtz(ct[2], ct[3]);
                    pd01 = (ct01 * mm01) * yw3h[2 * nt] + pd01;
                    pd23 = (ct23 * mm23) * yw3h[2 * nt + 1] + pd23;
                }
                hsq[tl] = hswap_add(pq01 + pq23);
                hsf[tl] = hswap_add(pf01 + pf23);
                hsd[tl] = hswap_add(pd01 + pd23);
            }
            // ONE cross-lane reduction for both tiles: low=tile0, high=tile1
            fp16x2 sq = cross_g_add(merge_lo_hi(hsq[0], hsq[1]));
            fp16x2 sf = cross_g_add(merge_lo_hi(hsf[0], hsf[1]));
            fp16x2 sd = cross_g_add(merge_lo_hi(hsd[0], hsd[1]));
            if (mt == g) { qsel = sq; fsel = sf; dsel = sd; }
        }

        #pragma unroll
        for (int tl = 0; tl < 2; ++tl) {
            float q  = (float)qsel[tl] + qb3;
            float Y  = (float)fsel[tl] + yb3;
            float dY = (float)dsel[tl];
            if (it > 0) {
                float resid = Y - residS[tl];
                loss = fmaf(resid, resid, loss);
            }
            YS[tl] = Y;
            if (it < NSTEPS) {
                residS[tl] = fmaf(SIGMA * dY, dwc[tl], fmaf(-0.5f * DT, q * q, Y));
                yS[tl] = fmaf(SIGMA, dwc[tl], fmaf(q, DT, yS[tl]));
            }
        }
        if (it < NSTEPS) t += DT;
    }

    // terminal: (YN - yN^2)^2, both tiles
    #pragma unroll
    for (int tl = 0; tl < 2; ++tl) {
        float tm = YS[tl] - yS[tl] * yS[tl];
        loss = fmaf(tm, tm, loss);
    }

    #pragma unroll
    for (int off = 1; off < 64; off <<= 1) loss += __shfl_xor(loss, off, 64);
    if (lane == 0) rb[wv] = loss;
    __syncthreads();
    if (tid == 0) atomicAdd(out, (rb[0] + rb[1] + rb[2] + rb[3]) * (1.0f / (float)B_TOT));
}

extern "C" void kernel_launch(void* const* d_in, const int* in_sizes, int n_in,
                              void* d_out, int out_size, void* d_ws, size_t ws_size,
                              hipStream_t stream) {
    const float* dW  = (const float*)d_in[0];
    const float* y0i = (const float*)d_in[1];
    const float* Yw1 = (const float*)d_in[2];
    const float* Yb1 = (const float*)d_in[3];
    const float* Yw2 = (const float*)d_in[4];
    const float* Yb2 = (const float*)d_in[5];
    const float* Yw3 = (const float*)d_in[6];
    const float* Yb3 = (const float*)d_in[7];
    const float* Qw1 = (const float*)d_in[8];
    const float* Qb1 = (const float*)d_in[9];
    const float* Qw2 = (const float*)d_in[10];
    const float* Qb2 = (const float*)d_in[11];
    const float* Qw3 = (const float*)d_in[12];
    const float* Qb3 = (const float*)d_in[13];
    float* out = (float*)d_out;

    hipLaunchKernelGGL(zero_out_k, dim3(1), dim3(1), 0, stream, out);
    hipLaunchKernelGGL(fbsnn_k, dim3(B_TOT / 512), dim3(256), 0, stream,
                       dW, y0i, Yw1, Yb1, Yw2, Yb2, Yw3, Yb3,
                       Qw1, Qb1, Qw2, Qb2, Qw3, Qb3, out);
}

// Round 17
// 471.403 us; speedup vs baseline: 5.6357x; 1.0892x over previous
//
#include <hip/hip_runtime.h>

// FBSNN: 50-step SDE loop, two 2-64-64-1 MLPs (Q control, Y value + dY/dy tangent).
// R17 (from R16 @492us): revert ONLY the fp32 bias-C-init (its 32 persistent regs
// caused a small spill: WRITE 3->13.7MB). Keep: 2-tile single-phase structure,
// epilogue consts in registers, merged two-tile cross-lane reduction.
// NEVER set min-waves >= 3 (R8/R10/R15 collapse).

#define B_TOT 262144
#define NSTEPS 50
#define DT 0.01f
#define SIGMA 0.5f

typedef _Float16 half8_t  __attribute__((ext_vector_type(8)));
typedef __fp16   fp16x2   __attribute__((ext_vector_type(2)));
typedef float    float4_t __attribute__((ext_vector_type(4)));
typedef int      int4_t   __attribute__((ext_vector_type(4)));

#define MFMA(a, b, c) __builtin_amdgcn_mfma_f32_16x16x32_f16((a), (b), (c), 0, 0, 0)

__device__ __forceinline__ half8_t pack4(fp16x2 a, fp16x2 b, fp16x2 c, fp16x2 d) {
    int4_t t;
    t[0] = __builtin_bit_cast(int, a);
    t[1] = __builtin_bit_cast(int, b);
    t[2] = __builtin_bit_cast(int, c);
    t[3] = __builtin_bit_cast(int, d);
    return __builtin_bit_cast(half8_t, t);
}

// horizontal add of the two fp16 halves (result in both halves)
__device__ __forceinline__ fp16x2 hswap_add(fp16x2 v) {
    unsigned u = __builtin_bit_cast(unsigned, v);
    unsigned s = (u >> 16) | (u << 16);
    return v + __builtin_bit_cast(fp16x2, s);
}
// merge: low half from a, high half from b
__device__ __forceinline__ fp16x2 merge_lo_hi(fp16x2 a, fp16x2 b) {
    unsigned ua = __builtin_bit_cast(unsigned, a);
    unsigned ub = __builtin_bit_cast(unsigned, b);
    return __builtin_bit_cast(fp16x2, (ua & 0xffffu) | (ub & 0xffff0000u));
}
// reduce across the 4 g-groups: xor16 (ds_swizzle) + xor32 (shfl)
__device__ __forceinline__ fp16x2 cross_g_add(fp16x2 v) {
    int o = __builtin_amdgcn_ds_swizzle(__builtin_bit_cast(int, v), 0x401F); // xor 16
    v = v + __builtin_bit_cast(fp16x2, o);
    int p = __shfl_xor(__builtin_bit_cast(int, v), 32, 64);
    v = v + __builtin_bit_cast(fp16x2, p);
    return v;
}

__device__ __forceinline__ float uniform_f(float x) {
    return __builtin_bit_cast(float, __builtin_amdgcn_readfirstlane(__builtin_bit_cast(int, x)));
}

__global__ void zero_out_k(float* out) { out[0] = 0.f; }

__global__ __launch_bounds__(256, 2) void fbsnn_k(
    const float* __restrict__ dW,  const float* __restrict__ y0i,
    const float* __restrict__ Yw1, const float* __restrict__ Yb1,
    const float* __restrict__ Yw2, const float* __restrict__ Yb2,
    const float* __restrict__ Yw3, const float* __restrict__ Yb3,
    const float* __restrict__ Qw1, const float* __restrict__ Qb1,
    const float* __restrict__ Qw2, const float* __restrict__ Qb2,
    const float* __restrict__ Qw3, const float* __restrict__ Qb3,
    float* __restrict__ out)
{
    // W2 transposed staging: w2[n*72 + k] = W2[k*64 + n]; read ONCE into registers.
    __shared__ __align__(16) _Float16 w2q[64 * 72];
    __shared__ __align__(16) _Float16 w2y[64 * 72];
    // layer1 consts fp32: [0..63]=w1_t row, [64..127]=w1_y row, [128..191]=b1
    __shared__ __align__(16) float l1q[192];
    __shared__ __align__(16) float l1y[192];
    __shared__ float rb[4];

    const int tid = threadIdx.x;

    #pragma unroll
    for (int it = 0; it < 16; ++it) {
        int e = it * 256 + tid;
        int k = e >> 6, n = e & 63;
        w2q[n * 72 + k] = (_Float16)Qw2[e];
        w2y[n * 72 + k] = (_Float16)Yw2[e];
    }
    if (tid < 64) {
        l1q[tid] = Qw1[tid]; l1q[64 + tid] = Qw1[64 + tid]; l1q[128 + tid] = Qb1[tid];
        l1y[tid] = Yw1[tid]; l1y[64 + tid] = Yw1[64 + tid]; l1y[128 + tid] = Yb1[tid];
    }
    __syncthreads();

    const int lane = tid & 63;
    const int wv   = tid >> 6;
    const int g    = lane >> 4;     // quad group 0..3
    const int c    = lane & 15;     // column within tile (= sample col)
    const int sA   = blockIdx.x * 512 + wv * 128 + lane;  // tile-0 global sample
    const int k0   = g * 8;         // this lane's k-slice base

    // ---- ALL weight fragments held in registers for the whole loop (32 VGPRs) ----
    half8_t wfq[4][2], wfy[4][2];
    #pragma unroll
    for (int nt = 0; nt < 4; ++nt) {
        const _Float16* bq = &w2q[(c + 16 * nt) * 72 + k0];
        const _Float16* by = &w2y[(c + 16 * nt) * 72 + k0];
        wfq[nt][0] = *(const half8_t*)bq;
        wfq[nt][1] = *(const half8_t*)(bq + 32);
        wfy[nt][0] = *(const half8_t*)by;
        wfy[nt][1] = *(const half8_t*)(by + 32);
    }

    // packed layer-1 y-row weights, held in regs for the whole loop
    fp16x2 wqh[8], wyh[8];
    #pragma unroll
    for (int j = 0; j < 8; ++j) {
        int idx = (j < 4) ? (k0 + 2 * j) : (32 + k0 + 2 * (j - 4));
        wqh[j] = fp16x2{(__fp16)l1q[64 + idx], (__fp16)l1q[64 + idx + 1]};
        wyh[j] = fp16x2{(__fp16)l1y[64 + idx], (__fp16)l1y[64 + idx + 1]};
    }

    // epilogue consts in registers, packed over r-pairs: n_out = nt*16 + g*4 + r
    fp16x2 qb2h[8], qw3h[8], yb2h[8], yw3h[8];
    #pragma unroll
    for (int nt = 0; nt < 4; ++nt) {
        #pragma unroll
        for (int p = 0; p < 2; ++p) {
            int nb = nt * 16 + g * 4 + 2 * p;
            qb2h[2 * nt + p] = __builtin_amdgcn_cvt_pkrtz(Qb2[nb], Qb2[nb + 1]);
            qw3h[2 * nt + p] = __builtin_amdgcn_cvt_pkrtz(Qw3[nb], Qw3[nb + 1]);
            yb2h[2 * nt + p] = __builtin_amdgcn_cvt_pkrtz(Yb2[nb], Yb2[nb + 1]);
            yw3h[2 * nt + p] = __builtin_amdgcn_cvt_pkrtz(Yw3[nb], Yw3[nb + 1]);
        }
    }

    const float qb3 = uniform_f(Qb3[0]);
    const float yb3 = uniform_f(Yb3[0]);

    const fp16x2 zero2 = {(__fp16)0.f, (__fp16)0.f};
    const fp16x2 one2  = {(__fp16)1.f, (__fp16)1.f};
    const fp16x2 big2  = {(__fp16)32768.f, (__fp16)32768.f};

    // two independent sample tiles per wave
    float yS[2], residS[2], YS[2], dwn[2];
    yS[0] = y0i[0];      yS[1] = yS[0];
    residS[0] = 0.f;     residS[1] = 0.f;
    YS[0] = 0.f;         YS[1] = 0.f;
    dwn[0] = dW[sA];     dwn[1] = dW[sA + 64];
    float t = 0.f, loss = 0.f;

    // NSTEPS+1 fused evals, ONE call site.
    #pragma unroll 1
    for (int it = 0; it <= NSTEPS; ++it) {
        float dwc[2] = {dwn[0], dwn[1]};
        int sn = (it < NSTEPS - 1) ? (it + 1) : (NSTEPS - 1);
        dwn[0] = dW[(size_t)sn * B_TOT + sA];
        dwn[1] = dW[(size_t)sn * B_TOT + sA + 64];

        // a-vector (t-dependent part of layer 1), packed fp16 — SHARED by both tiles
        fp16x2 aqh[8], ayh[8];
        #pragma unroll
        for (int h = 0; h < 2; ++h) {
            int kk = k0 + 32 * h;
            float4_t qt0 = *(const float4_t*)&l1q[kk];
            float4_t qt1 = *(const float4_t*)&l1q[kk + 4];
            float4_t qc0 = *(const float4_t*)&l1q[128 + kk];
            float4_t qc1 = *(const float4_t*)&l1q[128 + kk + 4];
            float4_t yt0 = *(const float4_t*)&l1y[kk];
            float4_t yt1 = *(const float4_t*)&l1y[kk + 4];
            float4_t yc0 = *(const float4_t*)&l1y[128 + kk];
            float4_t yc1 = *(const float4_t*)&l1y[128 + kk + 4];
            #pragma unroll
            for (int j = 0; j < 2; ++j) {
                float a0 = fmaf(t, qt0[2 * j], qc0[2 * j]);
                float a1 = fmaf(t, qt0[2 * j + 1], qc0[2 * j + 1]);
                float a2 = fmaf(t, qt1[2 * j], qc1[2 * j]);
                float a3 = fmaf(t, qt1[2 * j + 1], qc1[2 * j + 1]);
                aqh[4 * h + j]     = __builtin_amdgcn_cvt_pkrtz(a0, a1);
                aqh[4 * h + 2 + j] = __builtin_amdgcn_cvt_pkrtz(a2, a3);
                float b0 = fmaf(t, yt0[2 * j], yc0[2 * j]);
                float b1 = fmaf(t, yt0[2 * j + 1], yc0[2 * j + 1]);
                float b2 = fmaf(t, yt1[2 * j], yc1[2 * j]);
                float b3 = fmaf(t, yt1[2 * j + 1], yc1[2 * j + 1]);
                ayh[4 * h + j]     = __builtin_amdgcn_cvt_pkrtz(b0, b1);
                ayh[4 * h + 2 + j] = __builtin_amdgcn_cvt_pkrtz(b2, b3);
            }
        }

        fp16x2 qsel = zero2, fsel = zero2, dsel = zero2;  // low=tile0, high=tile1
        #pragma unroll
        for (int mt = 0; mt < 4; ++mt) {
            fp16x2 hsq[2], hsf[2], hsd[2];
            #pragma unroll
            for (int tl = 0; tl < 2; ++tl) {
                float ym = __shfl(yS[tl], mt * 16 + c, 64);
                fp16x2 ym2 = __builtin_amdgcn_cvt_pkrtz(ym, ym);

                fp16x2 hqa[8], hya[8], tda[8];
                #pragma unroll
                for (int j = 0; j < 8; ++j) {
                    hqa[j] = __builtin_elementwise_max((fp16x2)(wqh[j] * ym2 + aqh[j]), zero2);
                    fp16x2 hy = __builtin_elementwise_max((fp16x2)(wyh[j] * ym2 + ayh[j]), zero2);
                    hya[j] = hy;
                    fp16x2 mk = __builtin_elementwise_min((fp16x2)(hy * big2), one2);
                    tda[j] = mk * wyh[j];
                }
                half8_t qa_lo = pack4(hqa[0], hqa[1], hqa[2], hqa[3]);
                half8_t qa_hi = pack4(hqa[4], hqa[5], hqa[6], hqa[7]);
                half8_t yf_lo = pack4(hya[0], hya[1], hya[2], hya[3]);
                half8_t yf_hi = pack4(hya[4], hya[5], hya[6], hya[7]);
                half8_t td_lo = pack4(tda[0], tda[1], tda[2], tda[3]);
                half8_t td_hi = pack4(tda[4], tda[5], tda[6], tda[7]);

                fp16x2 pq01 = zero2, pq23 = zero2;
                fp16x2 pf01 = zero2, pf23 = zero2;
                fp16x2 pd01 = zero2, pd23 = zero2;
                #pragma unroll
                for (int nt = 0; nt < 4; ++nt) {
                    float4_t cq = {}, cf = {}, ct = {};
                    cq = MFMA(wfq[nt][0], qa_lo, cq);
                    cq = MFMA(wfq[nt][1], qa_hi, cq);
                    cf = MFMA(wfy[nt][0], yf_lo, cf);
                    cf = MFMA(wfy[nt][1], yf_hi, cf);
                    ct = MFMA(wfy[nt][0], td_lo, ct);
                    ct = MFMA(wfy[nt][1], td_hi, ct);
                    fp16x2 cq01 = __builtin_amdgcn_cvt_pkrtz(cq[0], cq[1]);
                    fp16x2 cq23 = __builtin_amdgcn_cvt_pkrtz(cq[2], cq[3]);
                    fp16x2 vq01 = __builtin_elementwise_max((fp16x2)(cq01 + qb2h[2 * nt]), zero2);
                    fp16x2 vq23 = __builtin_elementwise_max((fp16x2)(cq23 + qb2h[2 * nt + 1]), zero2);
                    pq01 = vq01 * qw3h[2 * nt] + pq01;
                    pq23 = vq23 * qw3h[2 * nt + 1] + pq23;
                    fp16x2 cf01 = __builtin_amdgcn_cvt_pkrtz(cf[0], cf[1]);
                    fp16x2 cf23 = __builtin_amdgcn_cvt_pkrtz(cf[2], cf[3]);
                    fp16x2 hf01 = __builtin_elementwise_max((fp16x2)(cf01 + yb2h[2 * nt]), zero2);
                    fp16x2 hf23 = __builtin_elementwise_max((fp16x2)(cf23 + yb2h[2 * nt + 1]), zero2);
                    pf01 = hf01 * yw3h[2 * nt] + pf01;
                    pf23 = hf23 * yw3h[2 * nt + 1] + pf23;
                    fp16x2 mm01 = __builtin_elementwise_min((fp16x2)(hf01 * big2), one2);
                    fp16x2 mm23 = __builtin_elementwise_min((fp16x2)(hf23 * big2), one2);
                    fp16x2 ct01 = __builtin_amdgcn_cvt_pkrtz(ct[0], ct[1]);
                    fp16x2 ct23 = __builtin_amdgcn_cvt_pkrtz(ct[2], ct[3]);
                    pd01 = (ct01 * mm01) * yw3h[2 * nt] + pd01;
                    pd23 = (ct23 * mm23) * yw3h[2 * nt + 1] + pd23;
                }
                hsq[tl] = hswap_add(pq01 + pq23);
                hsf[tl] = hswap_add(pf01 + pf23);
                hsd[tl] = hswap_add(pd01 + pd23);
            }
            // ONE cross-lane reduction for both tiles: low=tile0, high=tile1
            fp16x2 sq = cross_g_add(merge_lo_hi(hsq[0], hsq[1]));
            fp16x2 sf = cross_g_add(merge_lo_hi(hsf[0], hsf[1]));
            fp16x2 sd = cross_g_add(merge_lo_hi(hsd[0], hsd[1]));
            if (mt == g) { qsel = sq; fsel = sf; dsel = sd; }
        }

        #pragma unroll
        for (int tl = 0; tl < 2; ++tl) {
            float q  = (float)qsel[tl] + qb3;
            float Y  = (float)fsel[tl] + yb3;
            float dY = (float)dsel[tl];
            if (it > 0) {
                float resid = Y - residS[tl];
                loss = fmaf(resid, resid, loss);
            }
            YS[tl] = Y;
            if (it < NSTEPS) {
                residS[tl] = fmaf(SIGMA * dY, dwc[tl], fmaf(-0.5f * DT, q * q, Y));
                yS[tl] = fmaf(SIGMA, dwc[tl], fmaf(q, DT, yS[tl]));
            }
        }
        if (it < NSTEPS) t += DT;
    }

    // terminal: (YN - yN^2)^2, both tiles
    #pragma unroll
    for (int tl = 0; tl < 2; ++tl) {
        float tm = YS[tl] - yS[tl] * yS[tl];
        loss = fmaf(tm, tm, loss);
    }

    #pragma unroll
    for (int off = 1; off < 64; off <<= 1) loss += __shfl_xor(loss, off, 64);
    if (lane == 0) rb[wv] = loss;
    __syncthreads();
    if (tid == 0) atomicAdd(out, (rb[0] + rb[1] + rb[2] + rb[3]) * (1.0f / (float)B_TOT));
}

extern "C" void kernel_launch(void* const* d_in, const int* in_sizes, int n_in,
                              void* d_out, int out_size, void* d_ws, size_t ws_size,
                              hipStream_t stream) {
    const float* dW  = (const float*)d_in[0];
    const float* y0i = (const float*)d_in[1];
    const float* Yw1 = (const float*)d_in[2];
    const float* Yb1 = (const float*)d_in[3];
    const float* Yw2 = (const float*)d_in[4];
    const float* Yb2 = (const float*)d_in[5];
    const float* Yw3 = (const float*)d_in[6];
    const float* Yb3 = (const float*)d_in[7];
    const float* Qw1 = (const float*)d_in[8];
    const float* Qb1 = (const float*)d_in[9];
    const float* Qw2 = (const float*)d_in[10];
    const float* Qb2 = (const float*)d_in[11];
    const float* Qw3 = (const float*)d_in[12];
    const float* Qb3 = (const float*)d_in[13];
    float* out = (float*)d_out;

    hipLaunchKernelGGL(zero_out_k, dim3(1), dim3(1), 0, stream, out);
    hipLaunchKernelGGL(fbsnn_k, dim3(B_TOT / 512), dim3(256), 0, stream,
                       dW, y0i, Yw1, Yb1, Yw2, Yb2, Yw3, Yb3,
                       Qw1, Qb1, Qw2, Qb2, Qw3, Qb3, out);
}